// Round 6
// baseline (312.071 us; speedup 1.0000x reference)
//
#include <hip/hip_runtime.h>

// BoundaryChunker — MI355X (gfx950), round 6
// Round-6 change: GEMM register blocking 2x2 -> 4x4 fragments per wave
// (block 128x128, wave 64x64). Round 4/5 analysis: at 2x2 the load pipe is
// structurally oversubscribed (8KB per 12 MFMA ~ 140 B/cy/wave vs ~64 B/cy/CU
// load throughput); 4x4 halves bytes/MFMA and makes the 233-cy MFMA block per
// k-step long enough for distance-1 ping-pong prefetch to hide L2/L3 latency.
// No VGPR-clamping launch_bounds (round-3/4 mistake: (256,8) -> 32 VGPR ->
// serialized loads). Packed tile layout + split-K=4 + atomicAdd kept.

#define B_ 8
#define L_ 4096
#define D_ 1024
#define POOLW 5
#define EPS_ 1e-6f
#define KSPLIT 4
#define KCHUNK (D_ / KSPLIT)   // 256
#define NB_ 8                  // D_/128 n-tiles

typedef __attribute__((ext_vector_type(8))) short bf16x8;
typedef __attribute__((ext_vector_type(4))) float f32x4;

__device__ __forceinline__ unsigned short bf16_rne(float v) {
    unsigned u = __float_as_uint(v);
    unsigned r = u + 0x7FFFu + ((u >> 16) & 1u);
    return (unsigned short)(r >> 16);
}
__device__ __forceinline__ float bf16_f32(unsigned short h) {
    return __uint_as_float(((unsigned)h) << 16);
}

// packed element offset: tile16 = m>>4 owns contiguous [16*D_]; within, k-step
// ks=k>>5 owns 512 elems; lane-slot l=(m&15)+16*((k>>3)&3); elem = l*8+(k&7).
__device__ __forceinline__ size_t packed_off(int m, int k) {
    return (size_t)(m >> 4) * (16 * D_) + (size_t)(k >> 5) * 512 +
           (size_t)(((m & 15) + 16 * ((k >> 3) & 3)) * 8 + (k & 7));
}

__device__ __forceinline__ int mask_val(const void* mask, int flag, int i) {
    if (flag == 0) return ((const unsigned char*)mask)[i] != 0;
    if (flag == 1) return ((const int*)mask)[i] != 0;
    return ((const float*)mask)[i] != 0.0f;
}

// ------------------------------------------------------------------ pack ----
__global__ __launch_bounds__(256) void pack_kernel(
    const void* __restrict__ mask, const float* __restrict__ conf_in,
    int* __restrict__ counts, int* __restrict__ t_idx,
    float* __restrict__ out_mask, float* __restrict__ out_idx,
    float* __restrict__ out_conf, int U) {
    const int b   = blockIdx.x;
    const int tid = threadIdx.x;
    __shared__ int s_clo, s_chi, s_flag;
    __shared__ int scan[256];
    if (tid == 0) { s_clo = 0; s_chi = 0; }
    __syncthreads();
    // dtype detect on this block's 4KB slice of raw bytes:
    // i32(1) -> only byte%4==0 nonzero; f32(1.0f) -> only high bytes; u8 -> both.
    const uint4 wv = ((const uint4*)mask)[b * 256 + tid];
    const unsigned wd[4] = {wv.x, wv.y, wv.z, wv.w};
    int clo = 0, chi = 0;
#pragma unroll
    for (int i = 0; i < 4; ++i) {
        clo += ((wd[i] & 0x000000FFu) != 0u);
        chi += ((wd[i] & 0xFFFFFF00u) != 0u);
    }
    if (clo) atomicAdd(&s_clo, clo);
    if (chi) atomicAdd(&s_chi, chi);
    // zero-fill packed small outputs (d_out is re-poisoned before every call)
    for (int u = tid; u < U; u += 256) {
        out_mask[b * U + u] = 0.0f;
        out_idx[b * U + u]  = 0.0f;
        out_conf[b * U + u] = 0.0f;
    }
    __syncthreads();
    if (tid == 0) s_flag = (s_chi == 0) ? 1 : ((s_clo == 0) ? 2 : 0);
    __syncthreads();
    const int flag = s_flag;
    const int base = b * L_;
    int vals[16];
    int cnt = 0;
#pragma unroll
    for (int j = 0; j < 16; ++j) {
        int v = mask_val(mask, flag, base + tid * 16 + j);
        vals[j] = v;
        cnt += v;
    }
    scan[tid] = cnt;
    __syncthreads();
    for (int off = 1; off < 256; off <<= 1) {
        int v   = scan[tid];
        int add = (tid >= off) ? scan[tid - off] : 0;
        __syncthreads();
        scan[tid] = v + add;
        __syncthreads();
    }
    const int excl = scan[tid] - cnt;
    if (tid == 0) counts[b] = scan[255];
    int u = excl;
#pragma unroll
    for (int j = 0; j < 16; ++j) {
        if (vals[j]) {
            const int t = tid * 16 + j;
            t_idx[b * U + u]    = t;
            out_mask[b * U + u] = 1.0f;
            out_idx[b * U + u]  = (float)t;
            out_conf[b * U + u] = conf_in[base + t];
            ++u;
        }
    }
}

// ----------------------------------------------------------------- wconv ----
__global__ __launch_bounds__(256) void wconv_kernel(
    const float* __restrict__ W, unsigned short* __restrict__ Whi,
    unsigned short* __restrict__ Wlo) {
    const int i = (blockIdx.x * 256 + threadIdx.x) * 4;
    const int n = i >> 10, k = i & 1023;
    const float4 v = *(const float4*)&W[i];
    ushort4 hi, lo;
    hi.x = bf16_rne(v.x); lo.x = bf16_rne(v.x - bf16_f32(hi.x));
    hi.y = bf16_rne(v.y); lo.y = bf16_rne(v.y - bf16_f32(hi.y));
    hi.z = bf16_rne(v.z); lo.z = bf16_rne(v.z - bf16_f32(hi.z));
    hi.w = bf16_rne(v.w); lo.w = bf16_rne(v.w - bf16_f32(hi.w));
    const size_t o = packed_off(n, k);
    *(ushort4*)&Whi[o] = hi;
    *(ushort4*)&Wlo[o] = lo;
}

// ------------------------------------------------------------------ pool ----
__global__ __launch_bounds__(256) void pool_kernel(
    const float* __restrict__ emb, const float* __restrict__ cs,
    const int* __restrict__ counts, const int* __restrict__ t_idx,
    unsigned short* __restrict__ Phi, unsigned short* __restrict__ Plo,
    int U) {
    const int m = blockIdx.x;  // b*U + u
    const int b = m / U, u = m - b * U;
    if (u >= counts[b]) return;
    const int t     = t_idx[m];
    const int start = (t - POOLW + 1) > 0 ? (t - POOLW + 1) : 0;
    float wsum = 0.f;
    for (int s = start; s <= t; ++s) wsum += cs[b * L_ + s];
    const float inv = 1.0f / (wsum + EPS_);
    const int d0 = threadIdx.x * 4;
    float4 acc = make_float4(0.f, 0.f, 0.f, 0.f);
    for (int s = start; s <= t; ++s) {
        const float w  = cs[b * L_ + s];
        const float4 e = *(const float4*)&emb[((size_t)(b * L_ + s)) * D_ + d0];
        acc.x += w * e.x; acc.y += w * e.y; acc.z += w * e.z; acc.w += w * e.w;
    }
    acc.x *= inv; acc.y *= inv; acc.z *= inv; acc.w *= inv;
    ushort4 hi, lo;
    hi.x = bf16_rne(acc.x); lo.x = bf16_rne(acc.x - bf16_f32(hi.x));
    hi.y = bf16_rne(acc.y); lo.y = bf16_rne(acc.y - bf16_f32(hi.y));
    hi.z = bf16_rne(acc.z); lo.z = bf16_rne(acc.z - bf16_f32(hi.z));
    hi.w = bf16_rne(acc.w); lo.w = bf16_rne(acc.w - bf16_f32(hi.w));
    const size_t o = packed_off(m, d0);
    *(ushort4*)&Phi[o] = hi;
    *(ushort4*)&Plo[o] = lo;
}

// ------------------------------------------------------------------ gemm ----
// Split-K block = (mt,kt,nt): 128x128 partial over K-chunk 256, atomicAdd.
// 4 waves 2x2, wave = 64x64 = 4x4 fragments. Ping-pong register prefetch.
struct Frag {
    bf16x8 ah[4], al[4], bh[4], bl[4];
};

__device__ __forceinline__ void load_set(
    Frag& f, const unsigned short* __restrict__ Phi,
    const unsigned short* __restrict__ Plo,
    const unsigned short* __restrict__ Whi,
    const unsigned short* __restrict__ Wlo, size_t abase, size_t bbase,
    int ks) {
    const size_t s = (size_t)ks * 512;
#pragma unroll
    for (int i = 0; i < 4; ++i) {
        const size_t ao = abase + (size_t)i * (16 * D_) + s;
        const size_t bo = bbase + (size_t)i * (16 * D_) + s;
        f.ah[i] = *(const bf16x8*)(Phi + ao);
        f.al[i] = *(const bf16x8*)(Plo + ao);
        f.bh[i] = *(const bf16x8*)(Whi + bo);
        f.bl[i] = *(const bf16x8*)(Wlo + bo);
    }
}

__device__ __forceinline__ void mfma_set(const Frag& f, f32x4 acc[4][4]) {
    __builtin_amdgcn_s_setprio(1);
#pragma unroll
    for (int i = 0; i < 4; ++i)
#pragma unroll
        for (int j = 0; j < 4; ++j) {
            acc[i][j] = __builtin_amdgcn_mfma_f32_16x16x32_bf16(
                f.ah[i], f.bh[j], acc[i][j], 0, 0, 0);
            acc[i][j] = __builtin_amdgcn_mfma_f32_16x16x32_bf16(
                f.ah[i], f.bl[j], acc[i][j], 0, 0, 0);
            acc[i][j] = __builtin_amdgcn_mfma_f32_16x16x32_bf16(
                f.al[i], f.bh[j], acc[i][j], 0, 0, 0);
        }
    __builtin_amdgcn_s_setprio(0);
}

__global__ __launch_bounds__(256) void gemm_kernel(
    const unsigned short* __restrict__ Phi, const unsigned short* __restrict__ Plo,
    const unsigned short* __restrict__ Whi, const unsigned short* __restrict__ Wlo,
    const float* __restrict__ bias, const int* __restrict__ counts,
    float* __restrict__ C, int M, int U, int MB) {
    // bijective XCD swizzle; mt outermost -> per-XCD A-slice is L2-resident.
    const int nwg = MB * KSPLIT * NB_;
    const int q = nwg >> 3, r = nwg & 7;
    const int xcd = blockIdx.x & 7, pos = blockIdx.x >> 3;
    const int wg =
        (xcd < r ? xcd * (q + 1) : r * (q + 1) + (xcd - r) * q) + pos;
    const int mt  = wg / (KSPLIT * NB_);
    const int rem = wg - mt * (KSPLIT * NB_);
    const int kt  = rem >> 3;   // 0..KSPLIT-1
    const int nt  = rem & 7;

    const int tid  = threadIdx.x;
    const int w    = tid >> 6;
    const int lane = tid & 63;
    const int bm = mt * 128, bn = nt * 128, k0 = kt * KCHUNK;
    const int wm = (w >> 1) * 64, wn = (w & 1) * 64;

    // packed fragment bases (frag i adds i*16*D_)
    const size_t abase =
        (size_t)((bm + wm) >> 4) * (16 * D_) + (size_t)(k0 >> 5) * 512 + lane * 8;
    const size_t bbase =
        (size_t)((bn + wn) >> 4) * (16 * D_) + (size_t)(k0 >> 5) * 512 + lane * 8;

    f32x4 acc[4][4] = {};
    Frag f0, f1;
    load_set(f0, Phi, Plo, Whi, Wlo, abase, bbase, 0);
#pragma unroll
    for (int ks = 0; ks < KCHUNK / 32; ks += 2) {
        load_set(f1, Phi, Plo, Whi, Wlo, abase, bbase, ks + 1);
        mfma_set(f0, acc);
        if (ks + 2 < KCHUNK / 32)
            load_set(f0, Phi, Plo, Whi, Wlo, abase, bbase, ks + 2);
        mfma_set(f1, acc);
    }
    // epilogue: atomic accumulate; kt==0 adds bias; inactive rows skipped
    // (C pre-zeroed by memset, so inactive slots are exactly 0).
    const int lr = lane & 15;
    const int mrow = (lane >> 4) * 4;
#pragma unroll
    for (int i = 0; i < 4; ++i)
#pragma unroll
        for (int j = 0; j < 4; ++j) {
            const int n  = bn + wn + j * 16 + lr;
            const float bv = (kt == 0) ? bias[n] : 0.0f;
#pragma unroll
            for (int rr = 0; rr < 4; ++rr) {
                const int m = bm + wm + i * 16 + mrow + rr;
                if (m >= M) continue;
                const int b_ = m / U;
                const int u  = m - b_ * U;
                if (u < counts[b_])
                    atomicAdd(&C[(size_t)m * D_ + n], acc[i][j][rr] + bv);
            }
        }
}

// ---------------------------------------------------------------- launch ----
extern "C" void kernel_launch(void* const* d_in, const int* in_sizes, int n_in,
                              void* d_out, int out_size, void* d_ws,
                              size_t ws_size, hipStream_t stream) {
    const float* emb     = (const float*)d_in[0];
    const void*  mask    = d_in[1];
    const float* cs      = (const float*)d_in[2];
    const float* conf_in = (const float*)d_in[3];
    const float* W       = (const float*)d_in[4];
    const float* bias    = (const float*)d_in[5];

    const int U    = out_size / (B_ * (D_ + 3));
    const int M    = B_ * U;
    const int Mpad = (M + 127) & ~127;

    float* out_chunks = (float*)d_out;                  // (B,U,D)
    float* out_mask   = out_chunks + (size_t)M * D_;    // (B,U)
    float* out_idx    = out_mask + M;                   // (B,U)
    float* out_conf   = out_idx + M;                    // (B,U)

    // workspace layout (16B-aligned chunks)
    char* ws = (char*)d_ws;
    int* counts = (int*)ws;                                   // 8 ints
    int* t_idx  = (int*)(ws + 256);                           // Mpad ints
    size_t off  = (256 + (size_t)Mpad * 4 + 255) & ~(size_t)255;
    unsigned short* Phi = (unsigned short*)(ws + off);        // Mpad*D bf16 (packed)
    off += (size_t)Mpad * D_ * 2;
    unsigned short* Plo = (unsigned short*)(ws + off);
    off += (size_t)Mpad * D_ * 2;
    unsigned short* Whi = (unsigned short*)(ws + off);        // D*D bf16 (packed)
    off += (size_t)D_ * D_ * 2;
    unsigned short* Wlo = (unsigned short*)(ws + off);

    // chunks must start at 0 (atomic accumulation + inactive-slot zeros)
    hipMemsetAsync(out_chunks, 0, (size_t)M * D_ * sizeof(float), stream);

    pack_kernel<<<B_, 256, 0, stream>>>(mask, conf_in, counts, t_idx,
                                        out_mask, out_idx, out_conf, U);
    wconv_kernel<<<D_ * D_ / 1024, 256, 0, stream>>>(W, Whi, Wlo);
    pool_kernel<<<M, 256, 0, stream>>>(emb, cs, counts, t_idx, Phi, Plo, U);
    const int MB = Mpad / 128;
    gemm_kernel<<<MB * KSPLIT * NB_, 256, 0, stream>>>(
        Phi, Plo, Whi, Wlo, bias, counts, out_chunks, M, U, MB);
}

// Round 7
// 224.424 us; speedup vs baseline: 1.3905x; 1.3905x over previous
//
#include <hip/hip_runtime.h>

// BoundaryChunker — MI355X (gfx950), round 7
// Round-7 change: single-product FP16 MFMA GEMM, spill-free by construction.
// Rounds 2-6 post-mortem: WRITE_SIZE >> C-bytes proved every GEMM variant was
// scratch-spill-bound (fragment arrays exceeded VGPR budget; launch_bounds
// clamps made it worse). Fix: fp16 single product (error ~9e-4 << 0.0078
// pooling-dominated absmax) -> 4 loads + 4 MFMA per k-step, 3-stage rotation
// fully unrolled (all compile-time indices), ~80 VGPR, no spills.
// No split-K: plain stores, no memset, no atomics. Packed tile layout kept.

#define B_ 8
#define L_ 4096
#define D_ 1024
#define POOLW 5
#define EPS_ 1e-6f
#define NB_ 16                 // D_/64 n-tiles

typedef __attribute__((ext_vector_type(8))) _Float16 f16x8;
typedef __attribute__((ext_vector_type(4))) float f32x4;

// packed element offset: tile16 = m>>4 owns contiguous [16*D_]; within, k-step
// ks=k>>5 owns 512 elems; lane-slot l=(m&15)+16*((k>>3)&3); elem = l*8+(k&7).
__device__ __forceinline__ size_t packed_off(int m, int k) {
    return (size_t)(m >> 4) * (16 * D_) + (size_t)(k >> 5) * 512 +
           (size_t)(((m & 15) + 16 * ((k >> 3) & 3)) * 8 + (k & 7));
}

__device__ __forceinline__ int mask_val(const void* mask, int flag, int i) {
    if (flag == 0) return ((const unsigned char*)mask)[i] != 0;
    if (flag == 1) return ((const int*)mask)[i] != 0;
    return ((const float*)mask)[i] != 0.0f;
}

// ------------------------------------------------------------------ pack ----
__global__ __launch_bounds__(256) void pack_kernel(
    const void* __restrict__ mask, const float* __restrict__ conf_in,
    int* __restrict__ counts, int* __restrict__ t_idx,
    float* __restrict__ out_mask, float* __restrict__ out_idx,
    float* __restrict__ out_conf, int U) {
    const int b   = blockIdx.x;
    const int tid = threadIdx.x;
    __shared__ int s_clo, s_chi, s_flag;
    __shared__ int scan[256];
    if (tid == 0) { s_clo = 0; s_chi = 0; }
    __syncthreads();
    // dtype detect on this block's 4KB slice of raw bytes:
    // i32(1) -> only byte%4==0 nonzero; f32(1.0f) -> only high bytes; u8 -> both.
    const uint4 wv = ((const uint4*)mask)[b * 256 + tid];
    const unsigned wd[4] = {wv.x, wv.y, wv.z, wv.w};
    int clo = 0, chi = 0;
#pragma unroll
    for (int i = 0; i < 4; ++i) {
        clo += ((wd[i] & 0x000000FFu) != 0u);
        chi += ((wd[i] & 0xFFFFFF00u) != 0u);
    }
    if (clo) atomicAdd(&s_clo, clo);
    if (chi) atomicAdd(&s_chi, chi);
    // zero-fill packed small outputs (d_out is re-poisoned before every call)
    for (int u = tid; u < U; u += 256) {
        out_mask[b * U + u] = 0.0f;
        out_idx[b * U + u]  = 0.0f;
        out_conf[b * U + u] = 0.0f;
    }
    __syncthreads();
    if (tid == 0) s_flag = (s_chi == 0) ? 1 : ((s_clo == 0) ? 2 : 0);
    __syncthreads();
    const int flag = s_flag;
    const int base = b * L_;
    int vals[16];
    int cnt = 0;
#pragma unroll
    for (int j = 0; j < 16; ++j) {
        int v = mask_val(mask, flag, base + tid * 16 + j);
        vals[j] = v;
        cnt += v;
    }
    scan[tid] = cnt;
    __syncthreads();
    for (int off = 1; off < 256; off <<= 1) {
        int v   = scan[tid];
        int add = (tid >= off) ? scan[tid - off] : 0;
        __syncthreads();
        scan[tid] = v + add;
        __syncthreads();
    }
    const int excl = scan[tid] - cnt;
    if (tid == 0) counts[b] = scan[255];
    int u = excl;
#pragma unroll
    for (int j = 0; j < 16; ++j) {
        if (vals[j]) {
            const int t = tid * 16 + j;
            t_idx[b * U + u]    = t;
            out_mask[b * U + u] = 1.0f;
            out_idx[b * U + u]  = (float)t;
            out_conf[b * U + u] = conf_in[base + t];
            ++u;
        }
    }
}

// ----------------------------------------------------------------- wconv ----
// W f32 [n][k] -> packed-tile fp16.
__global__ __launch_bounds__(256) void wconv_kernel(
    const float* __restrict__ W, _Float16* __restrict__ Wf) {
    const int i = (blockIdx.x * 256 + threadIdx.x) * 4;
    const int n = i >> 10, k = i & 1023;
    const float4 v = *(const float4*)&W[i];
    _Float16 h[4] = {(_Float16)v.x, (_Float16)v.y, (_Float16)v.z, (_Float16)v.w};
    *(ushort4*)&Wf[packed_off(n, k)] = *(const ushort4*)h;
}

// ------------------------------------------------------------------ pool ----
// One block per (b,u) slot; writes pooled vector into packed-tile fp16.
__global__ __launch_bounds__(256) void pool_kernel(
    const float* __restrict__ emb, const float* __restrict__ cs,
    const int* __restrict__ counts, const int* __restrict__ t_idx,
    _Float16* __restrict__ Pf, int U) {
    const int m = blockIdx.x;  // b*U + u
    const int b = m / U, u = m - b * U;
    if (u >= counts[b]) return;
    const int t     = t_idx[m];
    const int start = (t - POOLW + 1) > 0 ? (t - POOLW + 1) : 0;
    float wsum = 0.f;
    for (int s = start; s <= t; ++s) wsum += cs[b * L_ + s];
    const float inv = 1.0f / (wsum + EPS_);
    const int d0 = threadIdx.x * 4;
    float4 acc = make_float4(0.f, 0.f, 0.f, 0.f);
    for (int s = start; s <= t; ++s) {
        const float w  = cs[b * L_ + s];
        const float4 e = *(const float4*)&emb[((size_t)(b * L_ + s)) * D_ + d0];
        acc.x += w * e.x; acc.y += w * e.y; acc.z += w * e.z; acc.w += w * e.w;
    }
    _Float16 h[4] = {(_Float16)(acc.x * inv), (_Float16)(acc.y * inv),
                     (_Float16)(acc.z * inv), (_Float16)(acc.w * inv)};
    *(ushort4*)&Pf[packed_off(m, d0)] = *(const ushort4*)h;
}

// ------------------------------------------------------------------ gemm ----
// C[m,n] = sum_k P[m,k]*W[n,k] + bias[n], single-product fp16 MFMA.
// Block 64x64 (4 waves 2x2, wave 32x32 = 2x2 fragments). Full K per block,
// plain stores. 3-stage register rotation, prefetch distance 2, full unroll.
__global__ __launch_bounds__(256) void gemm_kernel(
    const _Float16* __restrict__ Pf, const _Float16* __restrict__ Wf,
    const float* __restrict__ bias, const int* __restrict__ counts,
    float* __restrict__ C, int M, int U, int MB) {
    // bijective XCD swizzle; mt outermost -> per-XCD A-slice is L2-resident.
    const int nwg = MB * NB_;
    const int q = nwg >> 3, r = nwg & 7;
    const int xcd = blockIdx.x & 7, pos = blockIdx.x >> 3;
    const int wg =
        (xcd < r ? xcd * (q + 1) : r * (q + 1) + (xcd - r) * q) + pos;
    const int mt = wg / NB_;
    const int nt = wg - mt * NB_;

    const int tid  = threadIdx.x;
    const int w    = tid >> 6;
    const int lane = tid & 63;
    const int bm = mt * 64, bn = nt * 64;
    const int wm = (w >> 1) * 32, wn = (w & 1) * 32;

    // packed fragment bases; fragment i adds i*16*D_, k-step ks adds ks*512
    const size_t abase =
        (size_t)((bm + wm) >> 4) * (16 * D_) + (size_t)lane * 8;
    const size_t bbase =
        (size_t)((bn + wn) >> 4) * (16 * D_) + (size_t)lane * 8;

    f16x8 a0[3], a1[3], b0[3], b1[3];   // 3-stage rotation
    f32x4 acc[2][2] = {};

#define LOADS(st, ks)                                                      \
    do {                                                                   \
        const size_t s_ = (size_t)(ks) * 512;                              \
        a0[st] = *(const f16x8*)(Pf + abase + s_);                         \
        a1[st] = *(const f16x8*)(Pf + abase + (size_t)(16 * D_) + s_);     \
        b0[st] = *(const f16x8*)(Wf + bbase + s_);                         \
        b1[st] = *(const f16x8*)(Wf + bbase + (size_t)(16 * D_) + s_);     \
    } while (0)

    LOADS(0, 0);
    LOADS(1, 1);
#pragma unroll
    for (int ks = 0; ks < 32; ++ks) {
        const int cur = ks % 3;
        if (ks + 2 < 32) LOADS((ks + 2) % 3, ks + 2);
        acc[0][0] = __builtin_amdgcn_mfma_f32_16x16x32_f16(a0[cur], b0[cur], acc[0][0], 0, 0, 0);
        acc[0][1] = __builtin_amdgcn_mfma_f32_16x16x32_f16(a0[cur], b1[cur], acc[0][1], 0, 0, 0);
        acc[1][0] = __builtin_amdgcn_mfma_f32_16x16x32_f16(a1[cur], b0[cur], acc[1][0], 0, 0, 0);
        acc[1][1] = __builtin_amdgcn_mfma_f32_16x16x32_f16(a1[cur], b1[cur], acc[1][1], 0, 0, 0);
    }
#undef LOADS

    // epilogue: bias; explicit 0 for inactive slots (no memset, plain stores)
    const int lr   = lane & 15;
    const int mrow = (lane >> 4) * 4;
#pragma unroll
    for (int i = 0; i < 2; ++i)
#pragma unroll
        for (int j = 0; j < 2; ++j) {
            const int n  = bn + wn + j * 16 + lr;
            const float bv = bias[n];
#pragma unroll
            for (int rr = 0; rr < 4; ++rr) {
                const int m = bm + wm + i * 16 + mrow + rr;
                if (m >= M) continue;
                const int b_ = m / U;
                const int u  = m - b_ * U;
                C[(size_t)m * D_ + n] =
                    (u < counts[b_]) ? (acc[i][j][rr] + bv) : 0.0f;
            }
        }
}

// ---------------------------------------------------------------- launch ----
extern "C" void kernel_launch(void* const* d_in, const int* in_sizes, int n_in,
                              void* d_out, int out_size, void* d_ws,
                              size_t ws_size, hipStream_t stream) {
    const float* emb     = (const float*)d_in[0];
    const void*  mask    = d_in[1];
    const float* cs      = (const float*)d_in[2];
    const float* conf_in = (const float*)d_in[3];
    const float* W       = (const float*)d_in[4];
    const float* bias    = (const float*)d_in[5];

    const int U    = out_size / (B_ * (D_ + 3));
    const int M    = B_ * U;
    const int Mpad = (M + 63) & ~63;

    float* out_chunks = (float*)d_out;                  // (B,U,D)
    float* out_mask   = out_chunks + (size_t)M * D_;    // (B,U)
    float* out_idx    = out_mask + M;                   // (B,U)
    float* out_conf   = out_idx + M;                    // (B,U)

    // workspace layout (16B-aligned chunks)
    char* ws = (char*)d_ws;
    int* counts = (int*)ws;                                   // 8 ints
    int* t_idx  = (int*)(ws + 256);                           // Mpad ints
    size_t off  = (256 + (size_t)Mpad * 4 + 255) & ~(size_t)255;
    _Float16* Pf = (_Float16*)(ws + off);                     // Mpad*D fp16 (packed)
    off += (size_t)Mpad * D_ * 2;
    _Float16* Wf = (_Float16*)(ws + off);                     // D*D fp16 (packed)

    pack_kernel<<<B_, 256, 0, stream>>>(mask, conf_in, counts, t_idx,
                                        out_mask, out_idx, out_conf, U);
    wconv_kernel<<<D_ * D_ / 1024, 256, 0, stream>>>(W, Wf);
    pool_kernel<<<M, 256, 0, stream>>>(emb, cs, counts, t_idx, Pf, U);
    const int MB = Mpad / 64;
    gemm_kernel<<<MB * NB_, 256, 0, stream>>>(Pf, Wf, bias, counts,
                                              out_chunks, M, U, MB);
}